// Round 4
// baseline (240.440 us; speedup 1.0000x reference)
//
#include <hip/hip_runtime.h>
#include <hip/hip_bf16.h>

// Problem constants
#define BS 16
#define LX 1024
#define LY 1024
#define H 512
#define MD 512
#define RY (BS * LY)   // 16384 rows of y

typedef __attribute__((ext_vector_type(8))) __bf16 bf16x8;
typedef __attribute__((ext_vector_type(4))) float floatx4;

// Async global->LDS, 16B per lane. HW dest = wave-uniform base + lane*16
// (guide §5 caveat m104/m108) — LDS layout must be contiguous in lane order.
__device__ __forceinline__ void load_lds16(const __bf16* g, __bf16* l) {
    __builtin_amdgcn_global_load_lds(
        (const __attribute__((address_space(1))) void*)g,
        (__attribute__((address_space(3))) void*)l,
        16, 0, 0);
}

// ---------------- prep_w2: f32 -> bf16 for W2 (1 MB read) + zero sync counters ----------------
__global__ __launch_bounds__(256) void prep_w2(const float* __restrict__ W2,
                                               __bf16* __restrict__ wb,
                                               int* __restrict__ cnt) {
    const int i = blockIdx.x * 256 + threadIdx.x;   // 0..32767, x8 floats
    if (blockIdx.x == 0 && threadIdx.x < BS) cnt[threadIdx.x] = 0;  // re-zeroed every iter (ws is poisoned)
    const float4 a = *(const float4*)(W2 + (size_t)i * 8);
    const float4 b = *(const float4*)(W2 + (size_t)i * 8 + 4);
    bf16x8 v = { (__bf16)a.x, (__bf16)a.y, (__bf16)a.z, (__bf16)a.w,
                 (__bf16)b.x, (__bf16)b.y, (__bf16)b.z, (__bf16)b.w };
    *(bf16x8*)(wb + (size_t)i * 8) = v;
}

// ---------------- gemm_smax: fused gemm + per-batch softmax broadcast ----------------
// Phase 1 (gemm) = exact R9 body (best measured): part[slice, m] = sum_n wo[n]*relu(Y@W2^T + b2).
//   Tile 64(M) x 128(N), BK=64, 4 waves 2x2, per-wave 32x64 via 2x4 fragments of
//   v_mfma_f32_16x16x32_bf16.
//   Bs swizzle: LDS slot s (16B granule) of row R stores global granule s^(R&7);
//     DMA lane (lrow=lane>>3, s=lane&7) fetches granule s^lrow; read slot
//     (kh*4+qa)^(la&7) -> conflict-free (R7/R8-proven).
//   A path: coalesced f32 float4 loads -> cvt bf16 -> padded LDS (ASTR=72).
//   XCD sibling swizzle: mt = ((id>>5)<<3)|(id&7); nt = (id>>3)&3.
// Phase 2 (softmax+bcast, same block): producer/consumer handoff via per-batch
//   counters. Each batch b (1024 part cols) is produced by exactly 64 blocks
//   (mt in [16b,16b+16) x 4 nt). A block broadcasts 16 output rows of the SAME
//   batch it produced (rank r = ((mt&15)<<2)|nt), gated on cnt[b]==64.
//   Coherence per G16 (XCD L2s not coherent): producer __threadfence (agent
//   writeback) before atomicAdd; consumer agent-scope ACQUIRE spin-load
//   (invalidates stale poison lines) before reading part. Bounded spin: fails
//   loud (absmax) rather than hanging.
//   Deadlock-free: grid 1024 = 4 blocks/CU guaranteed resident
//   (__launch_bounds__(256,4) caps VGPR at 128; LDS 25.7 KB -> 6/CU), and
//   every block produces before it consumes.
#define BM 64
#define BN 128
#define BKT 64
#define ASTR 72   // bf16 elems per A-row in LDS (144 B)
__global__ __launch_bounds__(256, 4) void gemm_smax(const float* __restrict__ Y,
                                                    const __bf16* __restrict__ wb,
                                                    const float* __restrict__ b2,
                                                    const float* __restrict__ wo,
                                                    float* __restrict__ part,
                                                    const int* __restrict__ mask,
                                                    floatx4* __restrict__ out,
                                                    int* __restrict__ cnt) {
    __shared__ __align__(16) __bf16 As[BM * ASTR];   // 9216 B, padded
    __shared__ __align__(16) __bf16 Bs[BN * BKT];    // 16384 B, swizzled (DMA dest)

    const int tid  = threadIdx.x;
    const int lane = tid & 63;
    const int wave = tid >> 6;
    const int wm = wave >> 1;
    const int wn = wave & 1;
    const int la = lane & 15;
    const int qa = lane >> 4;

    // XCD-sibling swizzle decode (1-D grid of 1024)
    const int id = blockIdx.x;
    const int mt = ((id >> 5) << 3) | (id & 7);   // 0..255
    const int nt = (id >> 3) & 3;                 // 0..3
    const int m0 = mt * BM, n0 = nt * BN;

    // B-staging geometry (lane-order DMA + XOR granule swizzle)
    const int lrow = lane >> 3;                        // 0..7
    const int lcol = ((lane & 7) ^ lrow) * 8;          // swizzled source granule

    // A-staging geometry: thread t -> row t>>2, 16 consecutive f32 at col (t&3)*16
    const int ar = tid >> 2;
    const int ac = (tid & 3) * 16;
    const float* ybase = Y + (size_t)(m0 + ar) * H + ac;

    floatx4 acc[2][4] = {};

    for (int k0 = 0; k0 < H; k0 += BKT) {
        __syncthreads();
        // B: async DMA first so it overlaps the A VGPR path. 4 rounds x (4 waves x 8 rows).
        #pragma unroll
        for (int r = 0; r < 4; ++r) {
            const int rb = r * 32 + wave * 8;   // rb+lrow ≡ lrow (mod 8)
            load_lds16(wb + (size_t)(n0 + rb + lrow) * H + k0 + lcol, &Bs[rb * BKT]);
        }
        // A: 16 f32 per thread -> 16 bf16 -> two 16B LDS writes (padded stride).
        const float4 a0 = *(const float4*)(ybase + k0);
        const float4 a1 = *(const float4*)(ybase + k0 + 4);
        const float4 a2 = *(const float4*)(ybase + k0 + 8);
        const float4 a3 = *(const float4*)(ybase + k0 + 12);
        bf16x8 p0 = { (__bf16)a0.x, (__bf16)a0.y, (__bf16)a0.z, (__bf16)a0.w,
                      (__bf16)a1.x, (__bf16)a1.y, (__bf16)a1.z, (__bf16)a1.w };
        bf16x8 p1 = { (__bf16)a2.x, (__bf16)a2.y, (__bf16)a2.z, (__bf16)a2.w,
                      (__bf16)a3.x, (__bf16)a3.y, (__bf16)a3.z, (__bf16)a3.w };
        *(bf16x8*)&As[ar * ASTR + ac]     = p0;
        *(bf16x8*)&As[ar * ASTR + ac + 8] = p1;
        __syncthreads();   // drains lds-DMA (vmcnt) + ds_write (lgkmcnt)

        #pragma unroll
        for (int kh = 0; kh < 2; ++kh) {
            bf16x8 afr[2], bfr[4];
            #pragma unroll
            for (int mf = 0; mf < 2; ++mf)
                afr[mf] = *(const bf16x8*)&As[(wm * 32 + mf * 16 + la) * ASTR + kh * 32 + qa * 8];
            #pragma unroll
            for (int nf = 0; nf < 4; ++nf) {
                const int row  = wn * 64 + nf * 16 + la;
                const int slot = (kh * 4 + qa) ^ (la & 7);
                bfr[nf] = *(const bf16x8*)&Bs[row * BKT + slot * 8];
            }
            #pragma unroll
            for (int mf = 0; mf < 2; ++mf)
                #pragma unroll
                for (int nf = 0; nf < 4; ++nf)
                    acc[mf][nf] = __builtin_amdgcn_mfma_f32_16x16x32_bf16(afr[mf], bfr[nf], acc[mf][nf], 0, 0, 0);
        }
    }

    // Epilogue: v = relu(acc + b2[n]); s = sum_n v*wo[n] over this wave's n-range;
    // xor-shuffle reduce across the 16 lanes of a row-group; deterministic store
    // into slice (nt*2 + wn) — no atomics, no zero-init needed.
    const int slice = nt * 2 + wn;
    #pragma unroll
    for (int mf = 0; mf < 2; ++mf) {
        #pragma unroll
        for (int reg = 0; reg < 4; ++reg) {
            float s = 0.f;
            #pragma unroll
            for (int nf = 0; nf < 4; ++nf) {
                const int n = n0 + wn * 64 + nf * 16 + la;
                float v = acc[mf][nf][reg] + b2[n];
                v = fmaxf(v, 0.f);
                s += v * wo[n];
            }
            s += __shfl_xor(s, 1);
            s += __shfl_xor(s, 2);
            s += __shfl_xor(s, 4);
            s += __shfl_xor(s, 8);
            if (la == 0) {
                const int m = m0 + wm * 32 + mf * 16 + qa * 4 + reg;
                part[(size_t)slice * RY + m] = s;
            }
        }
    }

    // ---- producer -> consumer handoff ----
    const int b = mt >> 4;                        // batch this block produced
    const int rk = ((mt & 15) << 2) | nt;         // rank 0..63 within batch
    __syncthreads();                              // all waves' part stores issued
    if (tid == 0) {
        __threadfence();                          // agent-scope: part visible device-wide
        atomicAdd(&cnt[b], 1);
    }
    if (tid == 0) {
        int tries = 0;
        while (__hip_atomic_load(&cnt[b], __ATOMIC_ACQUIRE, __HIP_MEMORY_SCOPE_AGENT) < 64) {
            __builtin_amdgcn_s_sleep(8);
            if (++tries > (1 << 26)) break;       // fail loud, never hang
        }
    }
    __syncthreads();                              // all threads ordered after acquire+inv

    // ---- phase 2: softmax + broadcast of 16 rows of batch b ----
    float* red = (float*)As;                      // reuse LDS
    const long base_row = (long)b * LX + (long)rk * 16;

    float vx = 0.f, vy = 0.f, vz = 0.f, vw = 0.f;
    #pragma unroll
    for (int t = 0; t < 8; ++t) {
        const float4 q = *(const float4*)(part + (size_t)t * RY + b * LY + tid * 4);
        vx += q.x; vy += q.y; vz += q.z; vw += q.w;
    }
    const int4 m4 = *(const int4*)(mask + b * LY + tid * 4);

    float mx = -INFINITY;
    if (!m4.x) mx = vx;
    if (!m4.y) mx = fmaxf(mx, vy);
    if (!m4.z) mx = fmaxf(mx, vz);
    if (!m4.w) mx = fmaxf(mx, vw);
    #pragma unroll
    for (int off = 1; off < 64; off <<= 1) mx = fmaxf(mx, __shfl_xor(mx, off));
    if ((tid & 63) == 0) red[tid >> 6] = mx;
    __syncthreads();
    mx = fmaxf(fmaxf(red[0], red[1]), fmaxf(red[2], red[3]));

    floatx4 e;
    e.x = m4.x ? 0.f : __expf(vx - mx);
    e.y = m4.y ? 0.f : __expf(vy - mx);
    e.z = m4.z ? 0.f : __expf(vz - mx);
    e.w = m4.w ? 0.f : __expf(vw - mx);
    float sum = e.x + e.y + e.z + e.w;
    #pragma unroll
    for (int off = 1; off < 64; off <<= 1) sum += __shfl_xor(sum, off);
    if ((tid & 63) == 0) red[4 + (tid >> 6)] = sum;
    __syncthreads();
    sum = red[4] + red[5] + red[6] + red[7];
    const float inv = 1.0f / sum;
    e.x *= inv; e.y *= inv; e.z *= inv; e.w *= inv;

    // 16 coalesced 4 KB row-writes (64 KB contiguous per block), non-temporal
    // (write-once stream, keep out of L2).
    floatx4* o = out + base_row * (LY / 4) + tid;
    #pragma unroll
    for (int r = 0; r < 16; ++r)
        __builtin_nontemporal_store(e, o + r * (LY / 4));
}

extern "C" void kernel_launch(void* const* d_in, const int* in_sizes, int n_in,
                              void* d_out, int out_size, void* d_ws, size_t ws_size,
                              hipStream_t stream) {
    // setup_inputs order: x, y, y_mask, W1, b1, W2, b2, w_o, b_o
    const float* y  = (const float*)d_in[1];
    const int*   ym = (const int*)  d_in[2];
    const float* W2 = (const float*)d_in[5];
    const float* b2 = (const float*)d_in[6];
    const float* wo = (const float*)d_in[7];
    // x, W1, b1, b_o are mathematically irrelevant to alpha (softmax shift-invariance).

    // Workspace layout (16B-aligned):
    char* ws = (char*)d_ws;
    __bf16* wb   = (__bf16*)ws;                          // MD*H bf16 = 0.5 MB
    float*  part = (float*)(ws + (size_t)MD * H * 2);    // 8*RY f32 = 0.5 MB
    int*    cnt  = (int*)(part + 8 * RY);                // BS ints

    prep_w2<<<(MD * H) / (256 * 8), 256, 0, stream>>>(W2, wb, cnt);
    gemm_smax<<<(MD / BN) * (RY / BM), 256, 0, stream>>>(y, wb, b2, wo, part, ym,
                                                         (floatx4*)d_out, cnt);   // 1024 blocks
}

// Round 5
// 224.008 us; speedup vs baseline: 1.0734x; 1.0734x over previous
//
#include <hip/hip_runtime.h>
#include <hip/hip_bf16.h>

// Problem constants
#define BS 16
#define LX 1024
#define LY 1024
#define H 512
#define MD 512
#define RY (BS * LY)   // 16384 rows of y

typedef __attribute__((ext_vector_type(8))) __bf16 bf16x8;
typedef __attribute__((ext_vector_type(4))) float floatx4;

// Async global->LDS, 16B per lane. HW dest = wave-uniform base + lane*16
// (guide §5 caveat m104/m108) — LDS layout must be contiguous in lane order.
__device__ __forceinline__ void load_lds16(const __bf16* g, __bf16* l) {
    __builtin_amdgcn_global_load_lds(
        (const __attribute__((address_space(1))) void*)g,
        (__attribute__((address_space(3))) void*)l,
        16, 0, 0);
}

// ---------------- prep_w2: f32 -> bf16 for W2 (1 MB read) + zero sync counters ----------------
__global__ __launch_bounds__(256) void prep_w2(const float* __restrict__ W2,
                                               __bf16* __restrict__ wb,
                                               int* __restrict__ cnt) {
    const int i = blockIdx.x * 256 + threadIdx.x;   // 0..32767, x8 floats
    if (blockIdx.x == 0 && threadIdx.x < BS) cnt[threadIdx.x] = 0;  // re-zeroed every iter (ws is poisoned)
    const float4 a = *(const float4*)(W2 + (size_t)i * 8);
    const float4 b = *(const float4*)(W2 + (size_t)i * 8 + 4);
    bf16x8 v = { (__bf16)a.x, (__bf16)a.y, (__bf16)a.z, (__bf16)a.w,
                 (__bf16)b.x, (__bf16)b.y, (__bf16)b.z, (__bf16)b.w };
    *(bf16x8*)(wb + (size_t)i * 8) = v;
}

// ---------------- gemm_smax: fused gemm + per-batch softmax broadcast ----------------
// Phase 1 (gemm) = exact R9 body: part[slice, m] = sum_n wo[n]*relu(Y@W2^T + b2).
// Handoff v2 (R4 post-mortem): R4's acquire-per-spin-iteration emitted a
// buffer_inv (full XCD-L2 invalidate) every ~1 µs per spinner -> L2 thrash
// stretched gemm 10x (MfmaUtil 2.2%, 147 µs). New protocol does ZERO bulk
// cache maintenance during compute:
//   * part stores: __hip_atomic_store RELAXED/AGENT (sc1 write-through; never
//     dirty in L2; visible at IF when vmcnt acks — drained by __syncthreads).
//   * producer signal: plain device-scope atomicAdd (executes at IF). No
//     __threadfence -> no buffer_wbl2.
//   * consumer spin: RELAXED agent loads (sc1 read from IF, NO invalidate),
//     then ONE acquire load after spin exit -> single buffer_inv per block,
//     issued only when all 64 producers of the batch are done. This evicts
//     the stale-clean poison lines so phase-2 plain float4 reads refetch the
//     write-through data from IF.
//   * Bounded spin: fails loud (absmax), never hangs.
// Deadlock-free: grid 1024 = 4 blocks/CU guaranteed resident
// (__launch_bounds__(256,4); LDS 25.7 KB -> 6/CU), every block produces
// before it consumes.
#define BM 64
#define BN 128
#define BKT 64
#define ASTR 72   // bf16 elems per A-row in LDS (144 B)
__global__ __launch_bounds__(256, 4) void gemm_smax(const float* __restrict__ Y,
                                                    const __bf16* __restrict__ wb,
                                                    const float* __restrict__ b2,
                                                    const float* __restrict__ wo,
                                                    float* __restrict__ part,
                                                    const int* __restrict__ mask,
                                                    floatx4* __restrict__ out,
                                                    int* __restrict__ cnt) {
    __shared__ __align__(16) __bf16 As[BM * ASTR];   // 9216 B, padded
    __shared__ __align__(16) __bf16 Bs[BN * BKT];    // 16384 B, swizzled (DMA dest)

    const int tid  = threadIdx.x;
    const int lane = tid & 63;
    const int wave = tid >> 6;
    const int wm = wave >> 1;
    const int wn = wave & 1;
    const int la = lane & 15;
    const int qa = lane >> 4;

    // XCD-sibling swizzle decode (1-D grid of 1024)
    const int id = blockIdx.x;
    const int mt = ((id >> 5) << 3) | (id & 7);   // 0..255
    const int nt = (id >> 3) & 3;                 // 0..3
    const int m0 = mt * BM, n0 = nt * BN;

    // B-staging geometry (lane-order DMA + XOR granule swizzle)
    const int lrow = lane >> 3;                        // 0..7
    const int lcol = ((lane & 7) ^ lrow) * 8;          // swizzled source granule

    // A-staging geometry: thread t -> row t>>2, 16 consecutive f32 at col (t&3)*16
    const int ar = tid >> 2;
    const int ac = (tid & 3) * 16;
    const float* ybase = Y + (size_t)(m0 + ar) * H + ac;

    floatx4 acc[2][4] = {};

    for (int k0 = 0; k0 < H; k0 += BKT) {
        __syncthreads();
        // B: async DMA first so it overlaps the A VGPR path. 4 rounds x (4 waves x 8 rows).
        #pragma unroll
        for (int r = 0; r < 4; ++r) {
            const int rb = r * 32 + wave * 8;   // rb+lrow ≡ lrow (mod 8)
            load_lds16(wb + (size_t)(n0 + rb + lrow) * H + k0 + lcol, &Bs[rb * BKT]);
        }
        // A: 16 f32 per thread -> 16 bf16 -> two 16B LDS writes (padded stride).
        const float4 a0 = *(const float4*)(ybase + k0);
        const float4 a1 = *(const float4*)(ybase + k0 + 4);
        const float4 a2 = *(const float4*)(ybase + k0 + 8);
        const float4 a3 = *(const float4*)(ybase + k0 + 12);
        bf16x8 p0 = { (__bf16)a0.x, (__bf16)a0.y, (__bf16)a0.z, (__bf16)a0.w,
                      (__bf16)a1.x, (__bf16)a1.y, (__bf16)a1.z, (__bf16)a1.w };
        bf16x8 p1 = { (__bf16)a2.x, (__bf16)a2.y, (__bf16)a2.z, (__bf16)a2.w,
                      (__bf16)a3.x, (__bf16)a3.y, (__bf16)a3.z, (__bf16)a3.w };
        *(bf16x8*)&As[ar * ASTR + ac]     = p0;
        *(bf16x8*)&As[ar * ASTR + ac + 8] = p1;
        __syncthreads();   // drains lds-DMA (vmcnt) + ds_write (lgkmcnt)

        #pragma unroll
        for (int kh = 0; kh < 2; ++kh) {
            bf16x8 afr[2], bfr[4];
            #pragma unroll
            for (int mf = 0; mf < 2; ++mf)
                afr[mf] = *(const bf16x8*)&As[(wm * 32 + mf * 16 + la) * ASTR + kh * 32 + qa * 8];
            #pragma unroll
            for (int nf = 0; nf < 4; ++nf) {
                const int row  = wn * 64 + nf * 16 + la;
                const int slot = (kh * 4 + qa) ^ (la & 7);
                bfr[nf] = *(const bf16x8*)&Bs[row * BKT + slot * 8];
            }
            #pragma unroll
            for (int mf = 0; mf < 2; ++mf)
                #pragma unroll
                for (int nf = 0; nf < 4; ++nf)
                    acc[mf][nf] = __builtin_amdgcn_mfma_f32_16x16x32_bf16(afr[mf], bfr[nf], acc[mf][nf], 0, 0, 0);
        }
    }

    // Epilogue: v = relu(acc + b2[n]); s = sum_n v*wo[n] over this wave's n-range;
    // xor-shuffle reduce across the 16 lanes of a row-group; deterministic
    // sc1 write-through store into slice (nt*2 + wn) — no atomics RMW needed.
    const int slice = nt * 2 + wn;
    #pragma unroll
    for (int mf = 0; mf < 2; ++mf) {
        #pragma unroll
        for (int reg = 0; reg < 4; ++reg) {
            float s = 0.f;
            #pragma unroll
            for (int nf = 0; nf < 4; ++nf) {
                const int n = n0 + wn * 64 + nf * 16 + la;
                float v = acc[mf][nf][reg] + b2[n];
                v = fmaxf(v, 0.f);
                s += v * wo[n];
            }
            s += __shfl_xor(s, 1);
            s += __shfl_xor(s, 2);
            s += __shfl_xor(s, 4);
            s += __shfl_xor(s, 8);
            if (la == 0) {
                const int m = m0 + wm * 32 + mf * 16 + qa * 4 + reg;
                __hip_atomic_store(&part[(size_t)slice * RY + m], s,
                                   __ATOMIC_RELAXED, __HIP_MEMORY_SCOPE_AGENT);
            }
        }
    }

    // ---- producer -> consumer handoff (no bulk cache ops while gemm runs) ----
    const int b = mt >> 4;                        // batch this block produced
    const int rk = ((mt & 15) << 2) | nt;         // rank 0..63 within batch
    __syncthreads();                              // per-wave vmcnt(0): sc1 stores acked at IF
    if (tid == 0) {
        atomicAdd(&cnt[b], 1);                    // device-scope, executes at IF
        int tries = 0;
        while (__hip_atomic_load(&cnt[b], __ATOMIC_RELAXED, __HIP_MEMORY_SCOPE_AGENT) < 64) {
            __builtin_amdgcn_s_sleep(16);
            if (++tries > 200000) break;          // fail loud, never hang
        }
        // ONE acquire -> single buffer_inv, after all producers are done:
        // evicts stale-clean poison lines so phase-2 plain reads refetch from IF.
        (void)__hip_atomic_load(&cnt[b], __ATOMIC_ACQUIRE, __HIP_MEMORY_SCOPE_AGENT);
    }
    __syncthreads();                              // all threads ordered after the inv

    // ---- phase 2: softmax + broadcast of 16 rows of batch b (R3 body) ----
    float* red = (float*)As;                      // reuse LDS
    const long base_row = (long)b * LX + (long)rk * 16;

    float vx = 0.f, vy = 0.f, vz = 0.f, vw = 0.f;
    #pragma unroll
    for (int t = 0; t < 8; ++t) {
        const float4 q = *(const float4*)(part + (size_t)t * RY + b * LY + tid * 4);
        vx += q.x; vy += q.y; vz += q.z; vw += q.w;
    }
    const int4 m4 = *(const int4*)(mask + b * LY + tid * 4);

    float mx = -INFINITY;
    if (!m4.x) mx = vx;
    if (!m4.y) mx = fmaxf(mx, vy);
    if (!m4.z) mx = fmaxf(mx, vz);
    if (!m4.w) mx = fmaxf(mx, vw);
    #pragma unroll
    for (int off = 1; off < 64; off <<= 1) mx = fmaxf(mx, __shfl_xor(mx, off));
    if ((tid & 63) == 0) red[tid >> 6] = mx;
    __syncthreads();
    mx = fmaxf(fmaxf(red[0], red[1]), fmaxf(red[2], red[3]));

    floatx4 e;
    e.x = m4.x ? 0.f : __expf(vx - mx);
    e.y = m4.y ? 0.f : __expf(vy - mx);
    e.z = m4.z ? 0.f : __expf(vz - mx);
    e.w = m4.w ? 0.f : __expf(vw - mx);
    float sum = e.x + e.y + e.z + e.w;
    #pragma unroll
    for (int off = 1; off < 64; off <<= 1) sum += __shfl_xor(sum, off);
    if ((tid & 63) == 0) red[4 + (tid >> 6)] = sum;
    __syncthreads();
    sum = red[4] + red[5] + red[6] + red[7];
    const float inv = 1.0f / sum;
    e.x *= inv; e.y *= inv; e.z *= inv; e.w *= inv;

    // 16 coalesced 4 KB row-writes (64 KB contiguous per block), non-temporal
    // (write-once stream, keep out of L2).
    floatx4* o = out + base_row * (LY / 4) + tid;
    #pragma unroll
    for (int r = 0; r < 16; ++r)
        __builtin_nontemporal_store(e, o + r * (LY / 4));
}

extern "C" void kernel_launch(void* const* d_in, const int* in_sizes, int n_in,
                              void* d_out, int out_size, void* d_ws, size_t ws_size,
                              hipStream_t stream) {
    // setup_inputs order: x, y, y_mask, W1, b1, W2, b2, w_o, b_o
    const float* y  = (const float*)d_in[1];
    const int*   ym = (const int*)  d_in[2];
    const float* W2 = (const float*)d_in[5];
    const float* b2 = (const float*)d_in[6];
    const float* wo = (const float*)d_in[7];
    // x, W1, b1, b_o are mathematically irrelevant to alpha (softmax shift-invariance).

    // Workspace layout (16B-aligned):
    char* ws = (char*)d_ws;
    __bf16* wb   = (__bf16*)ws;                          // MD*H bf16 = 0.5 MB
    float*  part = (float*)(ws + (size_t)MD * H * 2);    // 8*RY f32 = 0.5 MB
    int*    cnt  = (int*)(part + 8 * RY);                // BS ints

    prep_w2<<<(MD * H) / (256 * 8), 256, 0, stream>>>(W2, wb, cnt);
    gemm_smax<<<(MD / BN) * (RY / BM), 256, 0, stream>>>(y, wb, b2, wo, part, ym,
                                                         (floatx4*)d_out, cnt);   // 1024 blocks
}

// Round 6
// 211.356 us; speedup vs baseline: 1.1376x; 1.0599x over previous
//
#include <hip/hip_runtime.h>
#include <hip/hip_bf16.h>

// Problem constants
#define BS 16
#define LX 1024
#define LY 1024
#define H 512
#define MD 512
#define RY (BS * LY)   // 16384 rows of y

typedef __attribute__((ext_vector_type(8))) __bf16 bf16x8;
typedef __attribute__((ext_vector_type(4))) float floatx4;

// Async global->LDS, 16B per lane. HW dest = wave-uniform base + lane*16
// (guide §5 caveat m104/m108) — LDS layout must be contiguous in lane order.
__device__ __forceinline__ void load_lds16(const __bf16* g, __bf16* l) {
    __builtin_amdgcn_global_load_lds(
        (const __attribute__((address_space(1))) void*)g,
        (__attribute__((address_space(3))) void*)l,
        16, 0, 0);
}

// ---------------- prep_w2: f32 -> bf16 for W2 (1 MB read) + zero sync counters ----------------
__global__ __launch_bounds__(256) void prep_w2(const float* __restrict__ W2,
                                               __bf16* __restrict__ wb,
                                               int* __restrict__ cnt) {
    const int i = blockIdx.x * 256 + threadIdx.x;   // 0..32767, x8 floats
    if (blockIdx.x == 0 && threadIdx.x < BS) cnt[threadIdx.x] = 0;  // re-zeroed every iter (ws is poisoned)
    const float4 a = *(const float4*)(W2 + (size_t)i * 8);
    const float4 b = *(const float4*)(W2 + (size_t)i * 8 + 4);
    bf16x8 v = { (__bf16)a.x, (__bf16)a.y, (__bf16)a.z, (__bf16)a.w,
                 (__bf16)b.x, (__bf16)b.y, (__bf16)b.z, (__bf16)b.w };
    *(bf16x8*)(wb + (size_t)i * 8) = v;
}

// ---------------- gemm_smax: fused gemm + per-batch softmax broadcast ----------------
// Phase 1 (gemm) = exact R9 body: part[slice, m] = sum_n wo[n]*relu(Y@W2^T + b2).
// Handoff v3 (R5 post-mortem): R5's RELAXED agent-scope spin-load was served
// by the local XCD L2's stale-clean copy of the cnt line — remote atomicAdds
// land at IF but nothing invalidates the local line, so the spin only
// progressed on random eviction (~100 µs idle; MfmaUtil 2.8% with MFMA-busy
// still = 3.3 µs -> pure wait, not thrash).  Fix: poll with a device-scope
// atomic RMW (atomicAdd(&cnt,0)).  Agent-scope RMWs cannot be satisfied by
// the non-coherent L2 — they execute at the IF coherence point (proven: the
// producer increments have been cross-XCD visible all along).  One IF
// round-trip per poll, NO buffer_inv per iteration (R4's mistake), and ONE
// post-spin ACQUIRE (single buffer_inv) to discard stale-clean part lines
// before phase-2 plain reads.
//   * part stores: __hip_atomic_store RELAXED/AGENT (sc1 write-through to IF;
//     drained by the __syncthreads vmcnt before the signal).  Proven correct
//     (R4/R5 absmax == R3's bit-exact value).
//   * Bounded spin: fails loud (absmax), never hangs.
// Deadlock-free: grid 1024 = 4 blocks/CU guaranteed resident
// (__launch_bounds__(256,4); LDS 25.7 KB -> 6/CU), every block produces
// before it consumes.
#define BM 64
#define BN 128
#define BKT 64
#define ASTR 72   // bf16 elems per A-row in LDS (144 B)
__global__ __launch_bounds__(256, 4) void gemm_smax(const float* __restrict__ Y,
                                                    const __bf16* __restrict__ wb,
                                                    const float* __restrict__ b2,
                                                    const float* __restrict__ wo,
                                                    float* __restrict__ part,
                                                    const int* __restrict__ mask,
                                                    floatx4* __restrict__ out,
                                                    int* __restrict__ cnt) {
    __shared__ __align__(16) __bf16 As[BM * ASTR];   // 9216 B, padded
    __shared__ __align__(16) __bf16 Bs[BN * BKT];    // 16384 B, swizzled (DMA dest)

    const int tid  = threadIdx.x;
    const int lane = tid & 63;
    const int wave = tid >> 6;
    const int wm = wave >> 1;
    const int wn = wave & 1;
    const int la = lane & 15;
    const int qa = lane >> 4;

    // XCD-sibling swizzle decode (1-D grid of 1024)
    const int id = blockIdx.x;
    const int mt = ((id >> 5) << 3) | (id & 7);   // 0..255
    const int nt = (id >> 3) & 3;                 // 0..3
    const int m0 = mt * BM, n0 = nt * BN;

    // B-staging geometry (lane-order DMA + XOR granule swizzle)
    const int lrow = lane >> 3;                        // 0..7
    const int lcol = ((lane & 7) ^ lrow) * 8;          // swizzled source granule

    // A-staging geometry: thread t -> row t>>2, 16 consecutive f32 at col (t&3)*16
    const int ar = tid >> 2;
    const int ac = (tid & 3) * 16;
    const float* ybase = Y + (size_t)(m0 + ar) * H + ac;

    floatx4 acc[2][4] = {};

    for (int k0 = 0; k0 < H; k0 += BKT) {
        __syncthreads();
        // B: async DMA first so it overlaps the A VGPR path. 4 rounds x (4 waves x 8 rows).
        #pragma unroll
        for (int r = 0; r < 4; ++r) {
            const int rb = r * 32 + wave * 8;   // rb+lrow ≡ lrow (mod 8)
            load_lds16(wb + (size_t)(n0 + rb + lrow) * H + k0 + lcol, &Bs[rb * BKT]);
        }
        // A: 16 f32 per thread -> 16 bf16 -> two 16B LDS writes (padded stride).
        const float4 a0 = *(const float4*)(ybase + k0);
        const float4 a1 = *(const float4*)(ybase + k0 + 4);
        const float4 a2 = *(const float4*)(ybase + k0 + 8);
        const float4 a3 = *(const float4*)(ybase + k0 + 12);
        bf16x8 p0 = { (__bf16)a0.x, (__bf16)a0.y, (__bf16)a0.z, (__bf16)a0.w,
                      (__bf16)a1.x, (__bf16)a1.y, (__bf16)a1.z, (__bf16)a1.w };
        bf16x8 p1 = { (__bf16)a2.x, (__bf16)a2.y, (__bf16)a2.z, (__bf16)a2.w,
                      (__bf16)a3.x, (__bf16)a3.y, (__bf16)a3.z, (__bf16)a3.w };
        *(bf16x8*)&As[ar * ASTR + ac]     = p0;
        *(bf16x8*)&As[ar * ASTR + ac + 8] = p1;
        __syncthreads();   // drains lds-DMA (vmcnt) + ds_write (lgkmcnt)

        #pragma unroll
        for (int kh = 0; kh < 2; ++kh) {
            bf16x8 afr[2], bfr[4];
            #pragma unroll
            for (int mf = 0; mf < 2; ++mf)
                afr[mf] = *(const bf16x8*)&As[(wm * 32 + mf * 16 + la) * ASTR + kh * 32 + qa * 8];
            #pragma unroll
            for (int nf = 0; nf < 4; ++nf) {
                const int row  = wn * 64 + nf * 16 + la;
                const int slot = (kh * 4 + qa) ^ (la & 7);
                bfr[nf] = *(const bf16x8*)&Bs[row * BKT + slot * 8];
            }
            #pragma unroll
            for (int mf = 0; mf < 2; ++mf)
                #pragma unroll
                for (int nf = 0; nf < 4; ++nf)
                    acc[mf][nf] = __builtin_amdgcn_mfma_f32_16x16x32_bf16(afr[mf], bfr[nf], acc[mf][nf], 0, 0, 0);
        }
    }

    // Epilogue: v = relu(acc + b2[n]); s = sum_n v*wo[n] over this wave's n-range;
    // xor-shuffle reduce across the 16 lanes of a row-group; deterministic
    // sc1 write-through store into slice (nt*2 + wn).
    const int slice = nt * 2 + wn;
    #pragma unroll
    for (int mf = 0; mf < 2; ++mf) {
        #pragma unroll
        for (int reg = 0; reg < 4; ++reg) {
            float s = 0.f;
            #pragma unroll
            for (int nf = 0; nf < 4; ++nf) {
                const int n = n0 + wn * 64 + nf * 16 + la;
                float v = acc[mf][nf][reg] + b2[n];
                v = fmaxf(v, 0.f);
                s += v * wo[n];
            }
            s += __shfl_xor(s, 1);
            s += __shfl_xor(s, 2);
            s += __shfl_xor(s, 4);
            s += __shfl_xor(s, 8);
            if (la == 0) {
                const int m = m0 + wm * 32 + mf * 16 + qa * 4 + reg;
                __hip_atomic_store(&part[(size_t)slice * RY + m], s,
                                   __ATOMIC_RELAXED, __HIP_MEMORY_SCOPE_AGENT);
            }
        }
    }

    // ---- producer -> consumer handoff (coherent RMW poll, no bulk cache ops) ----
    const int b = mt >> 4;                        // batch this block produced
    const int rk = ((mt & 15) << 2) | nt;         // rank 0..63 within batch
    __syncthreads();                              // per-wave vmcnt(0): sc1 stores acked at IF
    if (tid == 0) {
        atomicAdd(&cnt[b], 1);                    // device-scope RMW at IF
        int tries = 0;
        while (atomicAdd(&cnt[b], 0) < 64) {      // RMW poll: always fresh (IF), no inv
            __builtin_amdgcn_s_sleep(8);
            if (++tries > 100000) break;          // fail loud, never hang
        }
        // ONE acquire -> single buffer_inv, after all producers are done:
        // evicts stale-clean poison lines so phase-2 plain reads refetch from IF.
        (void)__hip_atomic_load(&cnt[b], __ATOMIC_ACQUIRE, __HIP_MEMORY_SCOPE_AGENT);
    }
    __syncthreads();                              // all threads ordered after the inv

    // ---- phase 2: softmax + broadcast of 16 rows of batch b (R3 body) ----
    float* red = (float*)As;                      // reuse LDS
    const long base_row = (long)b * LX + (long)rk * 16;

    float vx = 0.f, vy = 0.f, vz = 0.f, vw = 0.f;
    #pragma unroll
    for (int t = 0; t < 8; ++t) {
        const float4 q = *(const float4*)(part + (size_t)t * RY + b * LY + tid * 4);
        vx += q.x; vy += q.y; vz += q.z; vw += q.w;
    }
    const int4 m4 = *(const int4*)(mask + b * LY + tid * 4);

    float mx = -INFINITY;
    if (!m4.x) mx = vx;
    if (!m4.y) mx = fmaxf(mx, vy);
    if (!m4.z) mx = fmaxf(mx, vz);
    if (!m4.w) mx = fmaxf(mx, vw);
    #pragma unroll
    for (int off = 1; off < 64; off <<= 1) mx = fmaxf(mx, __shfl_xor(mx, off));
    if ((tid & 63) == 0) red[tid >> 6] = mx;
    __syncthreads();
    mx = fmaxf(fmaxf(red[0], red[1]), fmaxf(red[2], red[3]));

    floatx4 e;
    e.x = m4.x ? 0.f : __expf(vx - mx);
    e.y = m4.y ? 0.f : __expf(vy - mx);
    e.z = m4.z ? 0.f : __expf(vz - mx);
    e.w = m4.w ? 0.f : __expf(vw - mx);
    float sum = e.x + e.y + e.z + e.w;
    #pragma unroll
    for (int off = 1; off < 64; off <<= 1) sum += __shfl_xor(sum, off);
    if ((tid & 63) == 0) red[4 + (tid >> 6)] = sum;
    __syncthreads();
    sum = red[4] + red[5] + red[6] + red[7];
    const float inv = 1.0f / sum;
    e.x *= inv; e.y *= inv; e.z *= inv; e.w *= inv;

    // 16 coalesced 4 KB row-writes (64 KB contiguous per block), non-temporal
    // (write-once stream, keep out of L2).
    floatx4* o = out + base_row * (LY / 4) + tid;
    #pragma unroll
    for (int r = 0; r < 16; ++r)
        __builtin_nontemporal_store(e, o + r * (LY / 4));
}

extern "C" void kernel_launch(void* const* d_in, const int* in_sizes, int n_in,
                              void* d_out, int out_size, void* d_ws, size_t ws_size,
                              hipStream_t stream) {
    // setup_inputs order: x, y, y_mask, W1, b1, W2, b2, w_o, b_o
    const float* y  = (const float*)d_in[1];
    const int*   ym = (const int*)  d_in[2];
    const float* W2 = (const float*)d_in[5];
    const float* b2 = (const float*)d_in[6];
    const float* wo = (const float*)d_in[7];
    // x, W1, b1, b_o are mathematically irrelevant to alpha (softmax shift-invariance).

    // Workspace layout (16B-aligned):
    char* ws = (char*)d_ws;
    __bf16* wb   = (__bf16*)ws;                          // MD*H bf16 = 0.5 MB
    float*  part = (float*)(ws + (size_t)MD * H * 2);    // 8*RY f32 = 0.5 MB
    int*    cnt  = (int*)(part + 8 * RY);                // BS ints

    prep_w2<<<(MD * H) / (256 * 8), 256, 0, stream>>>(W2, wb, cnt);
    gemm_smax<<<(MD / BN) * (RY / BM), 256, 0, stream>>>(y, wb, b2, wo, part, ym,
                                                         (floatx4*)d_out, cnt);   // 1024 blocks
}

// Round 7
// 142.384 us; speedup vs baseline: 1.6887x; 1.4844x over previous
//
#include <hip/hip_runtime.h>
#include <hip/hip_bf16.h>

// Problem constants
#define BS 16
#define LX 1024
#define LY 1024
#define H 512
#define MD 512
#define RY (BS * LY)   // 16384 rows of y

typedef __attribute__((ext_vector_type(8))) __bf16 bf16x8;
typedef __attribute__((ext_vector_type(4))) float floatx4;

// Async global->LDS, 16B per lane. HW dest = wave-uniform base + lane*16
// (guide §5 caveat m104/m108) — LDS layout must be contiguous in lane order.
__device__ __forceinline__ void load_lds16(const __bf16* g, __bf16* l) {
    __builtin_amdgcn_global_load_lds(
        (const __attribute__((address_space(1))) void*)g,
        (__attribute__((address_space(3))) void*)l,
        16, 0, 0);
}

// ---------------- prep_w2: f32 -> bf16 for W2 only (1 MB read) ----------------
__global__ __launch_bounds__(256) void prep_w2(const float* __restrict__ W2,
                                               __bf16* __restrict__ wb) {
    const int i = blockIdx.x * 256 + threadIdx.x;   // 0..32767, x8 floats
    const float4 a = *(const float4*)(W2 + (size_t)i * 8);
    const float4 b = *(const float4*)(W2 + (size_t)i * 8 + 4);
    bf16x8 v = { (__bf16)a.x, (__bf16)a.y, (__bf16)a.z, (__bf16)a.w,
                 (__bf16)b.x, (__bf16)b.y, (__bf16)b.z, (__bf16)b.w };
    *(bf16x8*)(wb + (size_t)i * 8) = v;
}

// ---------------- gemm: part[slice, m] = sum_n wo[n]*relu(Y@W2^T + b2) ----------------
// R14 = exact revert to the R3-measured best (142.4 µs).  R4/R5/R6 proved the
// fused producer->consumer handoff loses ~90 µs to (inv-storm | stale-clean
// spin | same-line RMW saturation) — separate kernels with the stream
// dependency are strictly better on this problem size.
// Tile 64(M) x 128(N), BK=64, 4 waves 2x2, per-wave 32x64 via 2x4 fragments of
// v_mfma_f32_16x16x32_bf16.
// Bs swizzle: LDS slot s (16B granule) of row R stores global granule s^(R&7).
//   DMA:  lane (lrow=lane>>3, s=lane&7) fetches granule s^lrow (same cache lines).
//   Read: granule kh*4+qa of row R is at slot (kh*4+qa)^(R&7), R&7 = la&7
//         -> 16 la-lanes spread across all 8 slot groups (even = conflict-free).
// A path: coalesced f32 float4 loads -> cvt bf16 -> padded LDS (ASTR=72: banks
//   spread 4*(la+qa) mod 32 = even 8-lane groups, minimum cycles).
// XCD sibling swizzle: 4 n-tiles of an m-tile share id%8 -> same XCD:
//   mt = ((id>>5)<<3)|(id&7);  nt = (id>>3)&3.
// Fragment layouts (m89/m92/m97-verified):
//   A/B operand: lane l holds row (l&15), k = (l>>4)*8 + j, j=0..7
//   C/D:         col = lane&15 (N), row = (lane>>4)*4 + reg (M)
#define BM 64
#define BN 128
#define BKT 64
#define ASTR 72   // bf16 elems per A-row in LDS (144 B)
__global__ __launch_bounds__(256) void gemm_sy(const float* __restrict__ Y,
                                               const __bf16* __restrict__ wb,
                                               const float* __restrict__ b2,
                                               const float* __restrict__ wo,
                                               float* __restrict__ part) {
    __shared__ __align__(16) __bf16 As[BM * ASTR];   // 9216 B, padded
    __shared__ __align__(16) __bf16 Bs[BN * BKT];    // 16384 B, swizzled (DMA dest)

    const int tid  = threadIdx.x;
    const int lane = tid & 63;
    const int wave = tid >> 6;
    const int wm = wave >> 1;
    const int wn = wave & 1;
    const int la = lane & 15;
    const int qa = lane >> 4;

    // XCD-sibling swizzle decode (1-D grid of 1024)
    const int id = blockIdx.x;
    const int mt = ((id >> 5) << 3) | (id & 7);   // 0..255
    const int nt = (id >> 3) & 3;                 // 0..3
    const int m0 = mt * BM, n0 = nt * BN;

    // B-staging geometry (lane-order DMA + XOR granule swizzle)
    const int lrow = lane >> 3;                        // 0..7
    const int lcol = ((lane & 7) ^ lrow) * 8;          // swizzled source granule

    // A-staging geometry: thread t -> row t>>2, 16 consecutive f32 at col (t&3)*16
    const int ar = tid >> 2;
    const int ac = (tid & 3) * 16;
    const float* ybase = Y + (size_t)(m0 + ar) * H + ac;

    floatx4 acc[2][4] = {};

    for (int k0 = 0; k0 < H; k0 += BKT) {
        __syncthreads();
        // B: async DMA first so it overlaps the A VGPR path. 4 rounds x (4 waves x 8 rows).
        #pragma unroll
        for (int r = 0; r < 4; ++r) {
            const int rb = r * 32 + wave * 8;   // rb+lrow ≡ lrow (mod 8)
            load_lds16(wb + (size_t)(n0 + rb + lrow) * H + k0 + lcol, &Bs[rb * BKT]);
        }
        // A: 16 f32 per thread -> 16 bf16 -> two 16B LDS writes (padded stride).
        const float4 a0 = *(const float4*)(ybase + k0);
        const float4 a1 = *(const float4*)(ybase + k0 + 4);
        const float4 a2 = *(const float4*)(ybase + k0 + 8);
        const float4 a3 = *(const float4*)(ybase + k0 + 12);
        bf16x8 p0 = { (__bf16)a0.x, (__bf16)a0.y, (__bf16)a0.z, (__bf16)a0.w,
                      (__bf16)a1.x, (__bf16)a1.y, (__bf16)a1.z, (__bf16)a1.w };
        bf16x8 p1 = { (__bf16)a2.x, (__bf16)a2.y, (__bf16)a2.z, (__bf16)a2.w,
                      (__bf16)a3.x, (__bf16)a3.y, (__bf16)a3.z, (__bf16)a3.w };
        *(bf16x8*)&As[ar * ASTR + ac]     = p0;
        *(bf16x8*)&As[ar * ASTR + ac + 8] = p1;
        __syncthreads();   // drains lds-DMA (vmcnt) + ds_write (lgkmcnt)

        #pragma unroll
        for (int kh = 0; kh < 2; ++kh) {
            bf16x8 afr[2], bfr[4];
            #pragma unroll
            for (int mf = 0; mf < 2; ++mf)
                afr[mf] = *(const bf16x8*)&As[(wm * 32 + mf * 16 + la) * ASTR + kh * 32 + qa * 8];
            #pragma unroll
            for (int nf = 0; nf < 4; ++nf) {
                const int row  = wn * 64 + nf * 16 + la;
                const int slot = (kh * 4 + qa) ^ (la & 7);
                bfr[nf] = *(const bf16x8*)&Bs[row * BKT + slot * 8];
            }
            #pragma unroll
            for (int mf = 0; mf < 2; ++mf)
                #pragma unroll
                for (int nf = 0; nf < 4; ++nf)
                    acc[mf][nf] = __builtin_amdgcn_mfma_f32_16x16x32_bf16(afr[mf], bfr[nf], acc[mf][nf], 0, 0, 0);
        }
    }

    // Epilogue: v = relu(acc + b2[n]); s = sum_n v*wo[n] over this wave's n-range;
    // xor-shuffle reduce across the 16 lanes of a row-group; deterministic store
    // into slice (nt*2 + wn) — no atomics, no zero-init needed.
    const int slice = nt * 2 + wn;
    #pragma unroll
    for (int mf = 0; mf < 2; ++mf) {
        #pragma unroll
        for (int reg = 0; reg < 4; ++reg) {
            float s = 0.f;
            #pragma unroll
            for (int nf = 0; nf < 4; ++nf) {
                const int n = n0 + wn * 64 + nf * 16 + la;
                float v = acc[mf][nf][reg] + b2[n];
                v = fmaxf(v, 0.f);
                s += v * wo[n];
            }
            s += __shfl_xor(s, 1);
            s += __shfl_xor(s, 2);
            s += __shfl_xor(s, 4);
            s += __shfl_xor(s, 8);
            if (la == 0) {
                const int m = m0 + wm * 32 + mf * 16 + qa * 4 + reg;
                part[(size_t)slice * RY + m] = s;
            }
        }
    }
}

// ---------------- softmax_bcast: reduce 8 slices + masked softmax + broadcast ----------------
// Fusion of softmax_p + bcast: 16 rows/block (grid 1024) and non-temporal
// stores via clang ext-vector floatx4 (__builtin_nontemporal_store rejects
// HIP_vector_type float4). Output is write-once, never re-read: keep the
// 64 MiB stream out of L2.
// Masked entries exactly 0 (reference's exp(-1e7 - max) underflows to 0 in f32).
__global__ __launch_bounds__(256) void softmax_bcast(const float* __restrict__ part,
                                                     const int* __restrict__ mask,
                                                     floatx4* __restrict__ out) {
    const int tid = threadIdx.x;
    const long base_row = (long)blockIdx.x * 16;       // [0, BS*LX)
    const int b = (int)(base_row >> 10);               // 16 | 1024: rows share b
    __shared__ float red[8];

    // thread owns 4 consecutive cols j = tid*4 .. tid*4+3
    float vx = 0.f, vy = 0.f, vz = 0.f, vw = 0.f;
    #pragma unroll
    for (int t = 0; t < 8; ++t) {
        const float4 q = *(const float4*)(part + (size_t)t * RY + b * LY + tid * 4);
        vx += q.x; vy += q.y; vz += q.z; vw += q.w;
    }
    const int4 m4 = *(const int4*)(mask + b * LY + tid * 4);

    float mx = -INFINITY;
    if (!m4.x) mx = vx;
    if (!m4.y) mx = fmaxf(mx, vy);
    if (!m4.z) mx = fmaxf(mx, vz);
    if (!m4.w) mx = fmaxf(mx, vw);
    #pragma unroll
    for (int off = 1; off < 64; off <<= 1) mx = fmaxf(mx, __shfl_xor(mx, off));
    if ((tid & 63) == 0) red[tid >> 6] = mx;
    __syncthreads();
    mx = fmaxf(fmaxf(red[0], red[1]), fmaxf(red[2], red[3]));

    floatx4 e;
    e.x = m4.x ? 0.f : __expf(vx - mx);
    e.y = m4.y ? 0.f : __expf(vy - mx);
    e.z = m4.z ? 0.f : __expf(vz - mx);
    e.w = m4.w ? 0.f : __expf(vw - mx);
    float sum = e.x + e.y + e.z + e.w;
    #pragma unroll
    for (int off = 1; off < 64; off <<= 1) sum += __shfl_xor(sum, off);
    if ((tid & 63) == 0) red[4 + (tid >> 6)] = sum;
    __syncthreads();
    sum = red[4] + red[5] + red[6] + red[7];
    const float inv = 1.0f / sum;
    e.x *= inv; e.y *= inv; e.z *= inv; e.w *= inv;

    // 16 coalesced 4 KB row-writes (64 KB contiguous per block), non-temporal.
    floatx4* o = out + base_row * (LY / 4) + tid;
    #pragma unroll
    for (int r = 0; r < 16; ++r)
        __builtin_nontemporal_store(e, o + r * (LY / 4));
}

extern "C" void kernel_launch(void* const* d_in, const int* in_sizes, int n_in,
                              void* d_out, int out_size, void* d_ws, size_t ws_size,
                              hipStream_t stream) {
    // setup_inputs order: x, y, y_mask, W1, b1, W2, b2, w_o, b_o
    const float* y  = (const float*)d_in[1];
    const int*   ym = (const int*)  d_in[2];
    const float* W2 = (const float*)d_in[5];
    const float* b2 = (const float*)d_in[6];
    const float* wo = (const float*)d_in[7];
    // x, W1, b1, b_o are mathematically irrelevant to alpha (softmax shift-invariance).

    // Workspace layout (16B-aligned):
    char* ws = (char*)d_ws;
    __bf16* wb   = (__bf16*)ws;                          // MD*H bf16 = 0.5 MB
    float*  part = (float*)(ws + (size_t)MD * H * 2);    // 8*RY f32

    prep_w2<<<(MD * H) / (256 * 8), 256, 0, stream>>>(W2, wb);
    gemm_sy<<<(MD / BN) * (RY / BM), 256, 0, stream>>>(y, wb, b2, wo, part);     // 1024 blocks, swizzled
    softmax_bcast<<<(BS * LX) / 16, 256, 0, stream>>>(part, ym, (floatx4*)d_out); // 1024 blocks
}